// Round 7
// baseline (1669.266 us; speedup 1.0000x reference)
//
#include <hip/hip_runtime.h>
#include <stdint.h>
#include <stddef.h>

#define NEGF (-1.0e30f)
#define LOGK 8.31776616672f  // log(4096)

typedef _Float16 f16x8 __attribute__((ext_vector_type(8)));
typedef _Float16 f16x4 __attribute__((ext_vector_type(4)));
typedef float f32x4 __attribute__((ext_vector_type(4)));

constexpr int Bn = 32;
constexpr int Tn = 2000;
constexpr int Cn = 256;
constexpr int Un = 200;
constexpr int Sn = 2 * Un + 1;  // 401
constexpr float Kn = 4096.0f;
constexpr int CP = 264;  // st class-stride (f16)

// Raw workgroup barrier: drain LDS only; global loads stay in flight.
#define RAWBAR() __asm__ __volatile__("s_waitcnt lgkmcnt(0)\ns_barrier" ::: "memory")

#define MF(A_, B_, C_) __builtin_amdgcn_mfma_f32_16x16x32_f16(A_, B_, C_, 0, 0, 0)

__device__ __forceinline__ float lse3(float a, float b, float c) {
  float m = fmaxf(fmaxf(a, b), c);
  return m + __logf(__expf(a - m) + __expf(b - m) + __expf(c - m));
}

__device__ __forceinline__ int clampi(int v, int lo, int hi) {
  return v < lo ? lo : (v > hi ? hi : v);
}

// 34 blocks x 256 threads. Blocks 0-1: denominator (16 b each, MFMA-batched).
// Blocks 2-33: CTC numerator (1 b each).
// MFMA floor: 128 mfma_16x16x32/step/block / 4 SIMDs * 16cy = 512cy (invariant).
__global__ __launch_bounds__(256, 1) void fwd_kernel(
    const float* __restrict__ logp, const int* __restrict__ targets,
    const int* __restrict__ in_lens, const int* __restrict__ tgt_lens,
    const float* __restrict__ trans, const float* __restrict__ start,
    float* __restrict__ ws) {
  const int tid = threadIdx.x;
  const int bid = blockIdx.x;

  if (bid < 2) {
    // ============ denominator: D[j][b] = sum_i E^T[j,i] * st[i,b] ============
    const int b0 = 16 * bid;
    const int w = tid >> 6;     // wave 0..3: class-tiles 4w+T
    const int lane = tid & 63;
    const int low = lane & 15;  // batch column b (all 16 live)
    const int q8 = lane >> 4;

    __shared__ __align__(16) _Float16 stL[2][16][CP];  // st[b][class], exp domain
    __shared__ __align__(16) float Rp[2][16][20];      // 16 partials/b + pad

    const int Lb = clampi(in_lens[b0 + low], Sn, Tn);
    int Lmax = Sn;
#pragma unroll
    for (int bb = 0; bb < 16; ++bb)
      Lmax = max(Lmax, clampi(in_lens[b0 + bb], Sn, Tn));

    const int cbase = 64 * w + low;
    const int off0 = 64 * w + 4 * q8;
    const int off1 = off0 + 16, off2 = off0 + 32, off3 = off0 + 48;

// A-frag (E^T): lane(low=m,q8) holds E^T[class=64w+16T+low][i=32KK+8q8+J]
#define E1F(T, KK, J) \
  ((_Float16)__expf(trans[(32 * (KK) + 8 * q8 + (J)) * Cn + cbase + 16 * (T)]))
#define MKE(T, KK)                                                    \
  (f16x8){E1F(T, KK, 0), E1F(T, KK, 1), E1F(T, KK, 2), E1F(T, KK, 3), \
          E1F(T, KK, 4), E1F(T, KK, 5), E1F(T, KK, 6), E1F(T, KK, 7)}
    const f16x8 E0_0 = MKE(0, 0), E0_1 = MKE(0, 1), E0_2 = MKE(0, 2), E0_3 = MKE(0, 3);
    const f16x8 E0_4 = MKE(0, 4), E0_5 = MKE(0, 5), E0_6 = MKE(0, 6), E0_7 = MKE(0, 7);
    const f16x8 E1_0 = MKE(1, 0), E1_1 = MKE(1, 1), E1_2 = MKE(1, 2), E1_3 = MKE(1, 3);
    const f16x8 E1_4 = MKE(1, 4), E1_5 = MKE(1, 5), E1_6 = MKE(1, 6), E1_7 = MKE(1, 7);
    const f16x8 E2_0 = MKE(2, 0), E2_1 = MKE(2, 1), E2_2 = MKE(2, 2), E2_3 = MKE(2, 3);
    const f16x8 E2_4 = MKE(2, 4), E2_5 = MKE(2, 5), E2_6 = MKE(2, 6), E2_7 = MKE(2, 7);
    const f16x8 E3_0 = MKE(3, 0), E3_1 = MKE(3, 1), E3_2 = MKE(3, 2), E3_3 = MKE(3, 3);
    const f16x8 E3_4 = MKE(3, 4), E3_5 = MKE(3, 5), E3_6 = MKE(3, 6), E3_7 = MKE(3, 7);
#undef MKE
#undef E1F

    const float* lpb_my = logp + (size_t)(b0 + low) * Tn * Cn;

    // ---- init t=0: st = K*exp(start+lp0); Rp[0] = 16 per-lane partials ----
    {
      const float4 s0 = *(const float4*)(start + off0);
      const float4 s1 = *(const float4*)(start + off1);
      const float4 s2 = *(const float4*)(start + off2);
      const float4 s3 = *(const float4*)(start + off3);
      const float4 a0 = *(const float4*)(lpb_my + off0);
      const float4 a1 = *(const float4*)(lpb_my + off1);
      const float4 a2 = *(const float4*)(lpb_my + off2);
      const float4 a3 = *(const float4*)(lpb_my + off3);
      float rsum = 0.f;
#define INI(sv, av, off)                                                    \
  {                                                                         \
    float v0 = Kn * __expf(sv.x + av.x), v1 = Kn * __expf(sv.y + av.y);     \
    float v2 = Kn * __expf(sv.z + av.z), v3 = Kn * __expf(sv.w + av.w);     \
    rsum += (v0 + v1) + (v2 + v3);                                          \
    f16x4 pk = {(_Float16)v0, (_Float16)v1, (_Float16)v2, (_Float16)v3};    \
    *(f16x4*)&stL[0][low][off] = pk;                                        \
  }
      INI(s0, a0, off0) INI(s1, a1, off1) INI(s2, a2, off2) INI(s3, a3, off3)
#undef INI
      Rp[0][low][4 * q8 + w] = rsum;
    }
    float G = -LOGK, kprev = 1.0f;
    // 2-deep emission pipeline: ldA = frame 1, ldB = frame 2 (covers HBM lat.)
    float4 lA0 = *(const float4*)(lpb_my + Cn + off0);
    float4 lA1 = *(const float4*)(lpb_my + Cn + off1);
    float4 lA2 = *(const float4*)(lpb_my + Cn + off2);
    float4 lA3 = *(const float4*)(lpb_my + Cn + off3);
    float4 lB0 = *(const float4*)(lpb_my + 2 * Cn + off0);
    float4 lB1 = *(const float4*)(lpb_my + 2 * Cn + off1);
    float4 lB2 = *(const float4*)(lpb_my + 2 * Cn + off2);
    float4 lB3 = *(const float4*)(lpb_my + 2 * Cn + off3);
    RAWBAR();

#define WTILE(cT, pxT, offT)                                                \
  {                                                                         \
    const float r0 = cT[0] * pxT.x, r1 = cT[1] * pxT.y;                     \
    const float r2 = cT[2] * pxT.z, r3 = cT[3] * pxT.w;                     \
    rs_ += (r0 + r1) + (r2 + r3);                                           \
    f16x4 pk = {(_Float16)(r0 * kap_), (_Float16)(r1 * kap_),               \
                (_Float16)(r2 * kap_), (_Float16)(r3 * kap_)};              \
    *(f16x4*)&stL[pw_][low][offT] = pk;                                     \
  }

// One time step. B-frags hoisted before all MFMAs (8 independent ds_read_b128
// up front, not interleaved). Emission reload targets t+2. kappa path (Rp) is
// read up front and resolved during the MFMA phase.
#define DSTEP(T_, LD0, LD1, LD2, LD3)                                        \
  {                                                                          \
    const int pr_ = ((T_) - 1) & 1, pw_ = (T_) & 1;                          \
    const f16x8 bf0 = *(const f16x8*)&stL[pr_][low][8 * q8];                 \
    const f16x8 bf1 = *(const f16x8*)&stL[pr_][low][32 + 8 * q8];            \
    const f16x8 bf2 = *(const f16x8*)&stL[pr_][low][64 + 8 * q8];            \
    const f16x8 bf3 = *(const f16x8*)&stL[pr_][low][96 + 8 * q8];            \
    const f16x8 bf4 = *(const f16x8*)&stL[pr_][low][128 + 8 * q8];           \
    const f16x8 bf5 = *(const f16x8*)&stL[pr_][low][160 + 8 * q8];           \
    const f16x8 bf6 = *(const f16x8*)&stL[pr_][low][192 + 8 * q8];           \
    const f16x8 bf7 = *(const f16x8*)&stL[pr_][low][224 + 8 * q8];           \
    const float4 rp0 = *(const float4*)&Rp[pr_][low][0];                     \
    const float4 rp1 = *(const float4*)&Rp[pr_][low][4];                     \
    const float4 rp2 = *(const float4*)&Rp[pr_][low][8];                     \
    const float4 rp3 = *(const float4*)&Rp[pr_][low][12];                    \
    const float4 px0 = {__expf(LD0.x), __expf(LD0.y), __expf(LD0.z), __expf(LD0.w)}; \
    const float4 px1 = {__expf(LD1.x), __expf(LD1.y), __expf(LD1.z), __expf(LD1.w)}; \
    const float4 px2 = {__expf(LD2.x), __expf(LD2.y), __expf(LD2.z), __expf(LD2.w)}; \
    const float4 px3 = {__expf(LD3.x), __expf(LD3.y), __expf(LD3.z), __expf(LD3.w)}; \
    const int tn_ = ((T_) + 2 < Lmax) ? (T_) + 2 : Lmax - 1;                 \
    const float* nb_ = lpb_my + (size_t)tn_ * Cn;                            \
    LD0 = *(const float4*)(nb_ + off0);                                      \
    LD1 = *(const float4*)(nb_ + off1);                                      \
    LD2 = *(const float4*)(nb_ + off2);                                      \
    LD3 = *(const float4*)(nb_ + off3);                                      \
    f32x4 c0 = {0.f, 0.f, 0.f, 0.f}, c1 = c0, c2 = c0, c3 = c0;              \
    c0 = MF(E0_0, bf0, c0); c1 = MF(E1_0, bf0, c1);                          \
    c2 = MF(E2_0, bf0, c2); c3 = MF(E3_0, bf0, c3);                          \
    c0 = MF(E0_1, bf1, c0); c1 = MF(E1_1, bf1, c1);                          \
    c2 = MF(E2_1, bf1, c2); c3 = MF(E3_1, bf1, c3);                          \
    c0 = MF(E0_2, bf2, c0); c1 = MF(E1_2, bf2, c1);                          \
    c2 = MF(E2_2, bf2, c2); c3 = MF(E3_2, bf2, c3);                          \
    c0 = MF(E0_3, bf3, c0); c1 = MF(E1_3, bf3, c1);                          \
    c2 = MF(E2_3, bf3, c2); c3 = MF(E3_3, bf3, c3);                          \
    c0 = MF(E0_4, bf4, c0); c1 = MF(E1_4, bf4, c1);                          \
    c2 = MF(E2_4, bf4, c2); c3 = MF(E3_4, bf4, c3);                          \
    c0 = MF(E0_5, bf5, c0); c1 = MF(E1_5, bf5, c1);                          \
    c2 = MF(E2_5, bf5, c2); c3 = MF(E3_5, bf5, c3);                          \
    c0 = MF(E0_6, bf6, c0); c1 = MF(E1_6, bf6, c1);                          \
    c2 = MF(E2_6, bf6, c2); c3 = MF(E3_6, bf6, c3);                          \
    c0 = MF(E0_7, bf7, c0); c1 = MF(E1_7, bf7, c1);                          \
    c2 = MF(E2_7, bf7, c2); c3 = MF(E3_7, bf7, c3);                          \
    const float R_ =                                                         \
        (((rp0.x + rp0.y) + (rp0.z + rp0.w)) + ((rp1.x + rp1.y) + (rp1.z + rp1.w))) + \
        (((rp2.x + rp2.y) + (rp2.z + rp2.w)) + ((rp3.x + rp3.y) + (rp3.z + rp3.w))); \
    G -= __logf(kprev);                                                      \
    const float zeta_ = R_ * kprev;                                          \
    if ((T_) == Lb) ws[Bn + b0 + low] = G + __logf(zeta_);                   \
    const float kap_ = Kn * __frcp_rn(zeta_);                                \
    kprev = kap_;                                                            \
    float rs_ = 0.f;                                                         \
    WTILE(c0, px0, off0) WTILE(c1, px1, off1)                                \
    WTILE(c2, px2, off2) WTILE(c3, px3, off3)                                \
    Rp[pw_][low][4 * q8 + w] = rs_;                                          \
    RAWBAR();                                                                \
  }

    int t = 1;
    for (; t + 1 < Lmax; t += 2) {
      DSTEP(t, lA0, lA1, lA2, lA3)
      DSTEP(t + 1, lB0, lB1, lB2, lB3)
    }
    for (; t < Lmax; ++t) { DSTEP(t, lA0, lA1, lA2, lA3) }
#undef DSTEP
#undef WTILE

    // epilogue: b's with L == Lmax finish here
    {
      const int pr_ = (Lmax - 1) & 1;
      const float4 rp0 = *(const float4*)&Rp[pr_][low][0];
      const float4 rp1 = *(const float4*)&Rp[pr_][low][4];
      const float4 rp2 = *(const float4*)&Rp[pr_][low][8];
      const float4 rp3 = *(const float4*)&Rp[pr_][low][12];
      const float R_ =
          (((rp0.x + rp0.y) + (rp0.z + rp0.w)) + ((rp1.x + rp1.y) + (rp1.z + rp1.w))) +
          (((rp2.x + rp2.y) + (rp2.z + rp2.w)) + ((rp3.x + rp3.y) + (rp3.z + rp3.w)));
      G -= __logf(kprev);
      const float zeta_ = R_ * kprev;
      if (Lb == Lmax) ws[Bn + b0 + low] = G + __logf(zeta_);
    }
  } else {
    // ============ CTC numerator forward (log domain, 2 states/thread) ============
    const int b = bid - 2;
    const int L = clampi(in_lens[b], Sn, Tn);
    const int tl = clampi(tgt_lens[b], 1, Un);

    __shared__ float abuf[2][Sn + 3];  // +2 front pad (NEG), states at [s+2]
    const float* lpb = logp + (size_t)b * Tn * Cn;
    const int* tgtb = targets + b * Un;

    const int s1 = tid;        // states 0..255
    const int s2 = tid + 256;  // states 256..400 (valid if < Sn)
    int e1 = 0, e2 = 0;
    bool k1 = false, k2 = false;
    if (s1 & 1) {
      const int uu = (s1 - 1) >> 1;
      e1 = clampi(tgtb[uu], 1, Cn - 1);
      if (uu > 0) k1 = (e1 != clampi(tgtb[uu - 1], 1, Cn - 1));
    }
    if ((s2 < Sn) && (s2 & 1)) {
      const int uu = (s2 - 1) >> 1;
      e2 = clampi(tgtb[uu], 1, Cn - 1);
      k2 = (e2 != clampi(tgtb[uu - 1], 1, Cn - 1));
    }

    abuf[0][s1 + 2] = (s1 == 0) ? lpb[0] : (s1 == 1 ? lpb[e1] : NEGF);
    if (s2 < Sn) abuf[0][s2 + 2] = NEGF;
    if (tid < 2) { abuf[0][tid] = NEGF; abuf[1][tid] = NEGF; }
    float pe1 = lpb[Cn + e1];  // 2-deep emission pipeline
    float pe2 = lpb[Cn + e2];
    float pm1 = lpb[2 * Cn + e1];
    float pm2 = lpb[2 * Cn + e2];
    RAWBAR();

    int cur = 0;
    for (int t = 1; t < L; ++t) {
      const float em1 = pe1, em2 = pe2;
      const float* A = abuf[cur];
      float* Bv = abuf[cur ^ 1];
      {
        const float x = A[s1 + 2], y = A[s1 + 1];
        const float z = k1 ? A[s1] : NEGF;
        Bv[s1 + 2] = lse3(x, y, z) + em1;
      }
      if (s2 < Sn) {
        const float x = A[s2 + 2], y = A[s2 + 1];
        const float z = k2 ? A[s2] : NEGF;
        Bv[s2 + 2] = lse3(x, y, z) + em2;
      }
      pe1 = pm1;
      pe2 = pm2;
      const int tf = (t + 2 < L) ? t + 2 : L - 1;
      pm1 = lpb[(size_t)tf * Cn + e1];
      pm2 = lpb[(size_t)tf * Cn + e2];
      RAWBAR();
      cur ^= 1;
    }
    if (tid == 0) {
      const int l = 2 * tl;
      const float x = abuf[cur][l + 2], y = abuf[cur][l + 1];
      const float m = fmaxf(x, y);
      ws[b] = m + __logf(__expf(x - m) + __expf(y - m));
    }
  }
}

__global__ void finalize_kernel(const float* __restrict__ ws,
                                float* __restrict__ out) {
  const int tid = threadIdx.x;  // 64 threads, one wave
  float tot = 0.f, cnt = 0.f;
  if (tid < Bn) {
    const float tv = ws[tid] - ws[Bn + tid];  // num - DEN_SCALE*den
    const bool valid = tv > 0.5f * NEGF;
    tot = valid ? tv : 0.f;
    cnt = valid ? 1.f : 0.f;
  }
#pragma unroll
  for (int off = 32; off >= 1; off >>= 1) {
    tot += __shfl_xor(tot, off, 64);
    cnt += __shfl_xor(cnt, off, 64);
  }
  if (tid == 0) out[0] = -tot / fmaxf(cnt, 1.f);
}

extern "C" void kernel_launch(void* const* d_in, const int* in_sizes, int n_in,
                              void* d_out, int out_size, void* d_ws, size_t ws_size,
                              hipStream_t stream) {
  const float* logp = (const float*)d_in[0];
  const int* targets = (const int*)d_in[1];
  const int* in_lens = (const int*)d_in[2];
  const int* tgt_lens = (const int*)d_in[3];
  const float* trans = (const float*)d_in[4];
  const float* start = (const float*)d_in[5];
  float* ws = (float*)d_ws;
  float* out = (float*)d_out;
  (void)in_sizes; (void)n_in; (void)out_size; (void)ws_size;

  fwd_kernel<<<dim3(2 + Bn), dim3(256), 0, stream>>>(
      logp, targets, in_lens, tgt_lens, trans, start, ws);
  finalize_kernel<<<dim3(1), dim3(64), 0, stream>>>(ws, out);
}